// Round 6
// baseline (216.284 us; speedup 1.0000x reference)
//
#include <hip/hip_runtime.h>
#include <hip/hip_bf16.h>

// Problem constants
#define H 1024
#define NHEAD 16
#define HDIM 64
#define SEQ 2048
#define BATCH 2
#define M_TOT (BATCH * SEQ) // 4096 tokens
#define NQKV 3072           // fused QKV output cols

typedef __attribute__((ext_vector_type(8))) short bf16x8;  // 8 bf16 = 4 VGPRs (MFMA A/B frag)
typedef __attribute__((ext_vector_type(4))) float f32x4;   // 16x16 MFMA C/D frag
typedef __attribute__((ext_vector_type(16))) float f32x16; // 32x32 MFMA C/D frag

// (1/sqrt(HDIM)) * log2(e), folded into Q at the QKV-GEMM epilogue
#define C2_SCALE 0.18033688f

__device__ __forceinline__ unsigned short f2bf(float f) {
  union { float f; unsigned int u; } a;
  a.f = f;
  unsigned int u = a.u;
  return (unsigned short)((u + 0x7fffu + ((u >> 16) & 1u)) >> 16); // RNE
}

// packed f32x2 -> bf16x2 (v_cvt_pk_bf16_f32), low short = first arg
__device__ __forceinline__ unsigned int pkbf(float a, float b) {
  union { __hip_bfloat162 h; unsigned int u; } cv;
  cv.h = __float22bfloat162_rn(float2{a, b});
  return cv.u;
}

__device__ __forceinline__ float fast_exp2(float x) {
#if defined(__has_builtin) && __has_builtin(__builtin_amdgcn_exp2f)
  return __builtin_amdgcn_exp2f(x);
#else
  return exp2f(x);
#endif
}

// async global->LDS, 16B per lane. LDS dest is wave-uniform base + lane*16.
typedef const __attribute__((address_space(1))) void* gas1_t;
typedef __attribute__((address_space(3))) void* las3_t;
__device__ __forceinline__ void gload16(const void* g, void* l) {
  __builtin_amdgcn_global_load_lds((gas1_t)(unsigned long long)g,
                                   (las3_t)(unsigned int)(unsigned long long)l,
                                   16, 0, 0);
}

// ---------------------------------------------------------------------------
// Kernel 1 (fused): LayerNorm rows (blocks 0..4095) + weight bf16 cast
// (blocks 4096..8191).
// ---------------------------------------------------------------------------
__global__ __launch_bounds__(256) void ln_cast_kernel(const float* __restrict__ x,
                                                      const float* __restrict__ gamma,
                                                      const float* __restrict__ beta,
                                                      unsigned short* __restrict__ xn,
                                                      const float* __restrict__ w0,
                                                      const float* __restrict__ w1,
                                                      const float* __restrict__ w2,
                                                      const float* __restrict__ w3,
                                                      unsigned short* __restrict__ wdst) {
  const int t = threadIdx.x;
  if (blockIdx.x >= M_TOT) {
    const int cb = blockIdx.x - M_TOT;   // 0..4095
    const int y = cb >> 10;              // matrix index 0..3
    const float* s = (y == 0) ? w0 : (y == 1) ? w1 : (y == 2) ? w2 : w3;
    const int i = (cb & 1023) * 256 + t; // float4 index within matrix
    const float4 v = ((const float4*)s)[i];
    ushort4 o;
    o.x = f2bf(v.x);
    o.y = f2bf(v.y);
    o.z = f2bf(v.z);
    o.w = f2bf(v.w);
    ((ushort4*)(wdst + (size_t)y * H * H))[i] = o;
    return;
  }
  const int row = blockIdx.x;
  const float* xr = x + (size_t)row * H;
  float4 v = ((const float4*)xr)[t];
  float s = v.x + v.y + v.z + v.w;
  float s2 = v.x * v.x + v.y * v.y + v.z * v.z + v.w * v.w;
#pragma unroll
  for (int o = 32; o; o >>= 1) {
    s += __shfl_xor(s, o, 64);
    s2 += __shfl_xor(s2, o, 64);
  }
  __shared__ float red[8];
  const int wave = t >> 6;
  if ((t & 63) == 0) {
    red[wave] = s;
    red[wave + 4] = s2;
  }
  __syncthreads();
  const float ts = red[0] + red[1] + red[2] + red[3];
  const float ts2 = red[4] + red[5] + red[6] + red[7];
  const float mu = ts * (1.0f / (float)H);
  const float var = ts2 * (1.0f / (float)H) - mu * mu;
  const float rstd = rsqrtf(var + 1e-5f);
  const float4 g = ((const float4*)gamma)[t];
  const float4 b = ((const float4*)beta)[t];
  ushort4 o;
  o.x = f2bf((v.x - mu) * rstd * g.x + b.x);
  o.y = f2bf((v.y - mu) * rstd * g.y + b.y);
  o.z = f2bf((v.z - mu) * rstd * g.z + b.z);
  o.w = f2bf((v.w - mu) * rstd * g.w + b.w);
  ((ushort4*)(xn + (size_t)row * H))[t] = o;
}

// ---------------------------------------------------------------------------
// 128x128x(BK=32) bf16 GEMM, 32x32x16 MFMA, double-buffered, 1 barrier/iter.
// LDS tile layout [c-half][m][k-half]: byte offset = c*4096 + m*32 + h*16.
//   - global_load_lds: instr (wave w, c) covers m = w*32 + lane/2, h = lane&1
//     -> LDS chunk == lane (wave-uniform base + lane*16) and contiguous 1 KB.
//   - frag read (m-tile i, half c): lanes cover contiguous 1 KB -> conflict-free.
// Operand layout: A/B [m|n = lane&31][k = (lane>>5)*8 + j].
// C/D layout: col = lane&31, row = (r&3) + 8*(r>>2) + 4*(lane>>5), r in [0,16).
// EPI=0: QKV epilogue (Q prescaled by C2_SCALE; V stored transposed).
// EPI=1: proj epilogue -> fp32 out = acc + bo[col] + x (residual).
// ---------------------------------------------------------------------------
template <int EPI>
__global__ __launch_bounds__(256, 3) void gemm128(const unsigned short* __restrict__ A,
                                                  const unsigned short* __restrict__ W,
                                                  unsigned short* __restrict__ qk,
                                                  unsigned short* __restrict__ vt,
                                                  const float* __restrict__ bo,
                                                  const float* __restrict__ x,
                                                  float* __restrict__ out) {
  const int m0 = blockIdx.x * 128;
  const int n0 = blockIdx.y * 128;
  const int tid = threadIdx.x;
  const int wave = tid >> 6;
  const int lane = tid & 63;
  const int l32 = lane & 31;
  const int hh = lane >> 5;
  const int wx = wave & 1, wy = wave >> 1;

  // [buf][c][128 m][2 h][8 shorts] = 8192 shorts = 16 KB per matrix
  __shared__ __align__(16) unsigned short As[2 * 8192];
  __shared__ __align__(16) unsigned short Bs[2 * 8192];

  // staging: wave stages rows w*32..w*32+31; lane -> (row = lane/2, h = lane&1)
  const unsigned short* ag = A + (size_t)(m0 + wave * 32 + (lane >> 1)) * H + (lane & 1) * 8;
  const unsigned short* bg = W + (size_t)(n0 + wave * 32 + (lane >> 1)) * H + (lane & 1) * 8;
  const int lbase = wave * 512; // shorts: w*32 rows * 16 shorts-per-row-per-c

  f32x16 acc[2][2] = {};

  // prologue: stage k0=0 into buffer 0 (c in {0,1} halves of BK=32)
#pragma unroll
  for (int c = 0; c < 2; c++) {
    gload16(ag + c * 16, &As[c * 2048 + lbase]);
    gload16(bg + c * 16, &Bs[c * 2048 + lbase]);
  }

  for (int it = 0; it < H / 32; it++) {
    const int bi = it & 1;
    __syncthreads(); // drains buf[bi] loads (issued a full iter ago)
    if (it + 1 < H / 32) {
      const int k1 = (it + 1) * 32;
#pragma unroll
      for (int c = 0; c < 2; c++) {
        gload16(ag + k1 + c * 16, &As[(bi ^ 1) * 8192 + c * 2048 + lbase]);
        gload16(bg + k1 + c * 16, &Bs[(bi ^ 1) * 8192 + c * 2048 + lbase]);
      }
    }
    bf16x8 af[2][2], bf[2][2]; // [c][tile]
#pragma unroll
    for (int c = 0; c < 2; c++)
#pragma unroll
      for (int i = 0; i < 2; i++) {
        af[c][i] = *(const bf16x8*)&As[bi * 8192 + c * 2048 +
                                       (wy * 64 + i * 32 + l32) * 16 + hh * 8];
        bf[c][i] = *(const bf16x8*)&Bs[bi * 8192 + c * 2048 +
                                       (wx * 64 + i * 32 + l32) * 16 + hh * 8];
      }
#pragma unroll
    for (int c = 0; c < 2; c++)
#pragma unroll
      for (int i = 0; i < 2; i++)
#pragma unroll
        for (int j = 0; j < 2; j++)
          acc[i][j] =
              __builtin_amdgcn_mfma_f32_32x32x16_bf16(af[c][i], bf[c][j], acc[i][j], 0, 0, 0);
  }

  if (EPI == 0) {
#pragma unroll
    for (int j = 0; j < 2; j++) {
      const int cb = n0 + wx * 64 + j * 32; // wave-uniform tile col base
      if (cb < 2048) {
        const float qs = (cb < 1024) ? C2_SCALE : 1.0f;
#pragma unroll
        for (int i = 0; i < 2; i++)
#pragma unroll
          for (int r = 0; r < 16; r++) {
            const int row = m0 + wy * 64 + i * 32 + (r & 3) + 8 * (r >> 2) + 4 * hh;
            qk[(size_t)row * 2048 + cb + l32] = f2bf(acc[i][j][r] * qs);
          }
      } else {
        const int n = cb + l32 - 2048; // h*64+d
#pragma unroll
        for (int i = 0; i < 2; i++) {
          const int rb = m0 + wy * 64 + i * 32 + 4 * hh;
          const int b = rb >> 11;
          const int s0 = rb & 2047;
#pragma unroll
          for (int rg = 0; rg < 4; rg++) {
            ushort4 p;
            p.x = f2bf(acc[i][j][rg * 4 + 0]);
            p.y = f2bf(acc[i][j][rg * 4 + 1]);
            p.z = f2bf(acc[i][j][rg * 4 + 2]);
            p.w = f2bf(acc[i][j][rg * 4 + 3]);
            *(ushort4*)&vt[((size_t)b * 1024 + n) * SEQ + s0 + rg * 8] = p;
          }
        }
      }
    }
  } else {
#pragma unroll
    for (int j = 0; j < 2; j++) {
      const int col = n0 + wx * 64 + j * 32 + l32;
      const float bv = bo[col];
#pragma unroll
      for (int i = 0; i < 2; i++)
#pragma unroll
        for (int r = 0; r < 16; r++) {
          const int row = m0 + wy * 64 + i * 32 + (r & 3) + 8 * (r >> 2) + 4 * hh;
          const size_t idx = (size_t)row * H + col;
          out[idx] = acc[i][j][r] + bv + x[idx];
        }
    }
  }
}

// ---------------------------------------------------------------------------
// Flash attention v3.1: S^T = K·Q^T / O^T = V^T·P^T, fixed-max softmax.
// Changes vs v3: it-loop unrolled 2x (bi constant per copy -> swizzled LDS
// addresses loop-invariant/hoistable); l-sum split into 4 independent chains.
// ---------------------------------------------------------------------------
__global__ __launch_bounds__(256, 4) void attn_kernel(const unsigned short* __restrict__ qk,
                                                      const unsigned short* __restrict__ vt,
                                                      unsigned short* __restrict__ O) {
  const int qt = blockIdx.x;
  const int h = blockIdx.y;
  const int b = blockIdx.z;
  const int tid = threadIdx.x;
  const int wave = tid >> 6;
  const int lane = tid & 63;
  const int l16 = lane & 15;
  const int quad = lane >> 4;
  const int l8 = l16 & 7;

  __shared__ __align__(16) unsigned short Kt[2][64 * 64];
  __shared__ __align__(16) unsigned short Vt[2][64 * 64]; // [d][s]
  __shared__ __align__(16) unsigned short Pt[4][16 * 64]; // per-wave strip [qrow16][s64]

  const unsigned short* Qbase = qk + (size_t)b * SEQ * 2048 + h * 64;
  const unsigned short* Kbase = qk + (size_t)b * SEQ * 2048 + 1024 + h * 64;
  const unsigned short* Vbase = vt + ((size_t)b * 1024 + h * 64) * SEQ;

  // staging geometry: one gload16 covers 8 rows x 64 shorts (1 KB), XOR swizzle
  const int rIn = lane >> 3;
  const int gsw = (lane & 7) ^ rIn;
  const int ch0 = 2 * wave;

  // Q fragments (B-operand): B[n=l16 -> qrow][k=quad*8+j -> d]; c2 pre-folded
  const int qrow = qt * 64 + wave * 16 + l16;
  bf16x8 aq[2];
  aq[0] = *(const bf16x8*)(Qbase + (size_t)qrow * 2048 + quad * 8);
  aq[1] = *(const bf16x8*)(Qbase + (size_t)qrow * 2048 + 32 + quad * 8);

  float lacc[4] = {0.0f, 0.0f, 0.0f, 0.0f}; // 4 independent partial-l chains
  f32x4 o_acc[4] = {};                      // O^T: col=l16=qrow, row=quad*4+r -> d

  // prologue: stage tile 0 into buffer 0
#pragma unroll
  for (int c = 0; c < 2; c++) {
    const int ch = ch0 + c;
    const int row = ch * 8 + rIn;
    gload16(Kbase + (size_t)row * 2048 + gsw * 8, &Kt[0][ch * 512]);
    gload16(Vbase + (size_t)row * SEQ + gsw * 8, &Vt[0][ch * 512]);
  }

  unsigned short* myP = &Pt[wave][0];

#pragma unroll 2
  for (int it = 0; it < SEQ / 64; it++) {
    const int bi = it & 1;
    __syncthreads(); // waits cur-buffer loads (vmcnt) + prev iter readers done
    if (it + 1 < SEQ / 64) {
#pragma unroll
      for (int c = 0; c < 2; c++) {
        const int ch = ch0 + c;
        const int row = ch * 8 + rIn;
        gload16(Kbase + (size_t)((it + 1) * 64 + row) * 2048 + gsw * 8,
                &Kt[bi ^ 1][ch * 512]);
        gload16(Vbase + (size_t)row * SEQ + (it + 1) * 64 + gsw * 8,
                &Vt[bi ^ 1][ch * 512]);
      }
    }

    // S^T = K (A) @ Q^T (B): tile t -> kcols t*16+quad*4+r, qrow = l16
    f32x4 s[4] = {};
#pragma unroll
    for (int c = 0; c < 2; c++) {
#pragma unroll
      for (int t = 0; t < 4; t++) {
        const bf16x8 kf =
            *(const bf16x8*)&Kt[bi][(t * 16 + l16) * 64 + (((c * 4 + quad) ^ l8) * 8)];
        s[t] = __builtin_amdgcn_mfma_f32_16x16x32_bf16(kf, aq[c], s[t], 0, 0, 0);
      }
    }

    // fixed-max softmax: p = exp2(s); 4 independent l-chains (ILP)
    float pv[4][4];
#pragma unroll
    for (int t = 0; t < 4; t++) {
#pragma unroll
      for (int r = 0; r < 4; r++) pv[t][r] = fast_exp2(s[t][r]);
      lacc[t] += (pv[t][0] + pv[t][1]) + (pv[t][2] + pv[t][3]);
    }

    // P^T strip -> wave-private LDS (natural P layout [qrow][s]), b64 writes
#pragma unroll
    for (int t = 0; t < 4; t++) {
      uint2 d;
      d.x = pkbf(pv[t][0], pv[t][1]);
      d.y = pkbf(pv[t][2], pv[t][3]);
      *(uint2*)&myP[l16 * 64 + (((t * 2 + (quad >> 1)) ^ l8) * 8) + (quad & 1) * 4] = d;
    }

    // O^T += V^T (A) @ P^T (B)
#pragma unroll
    for (int c = 0; c < 2; c++) {
      const bf16x8 pb = *(const bf16x8*)&myP[l16 * 64 + (((c * 4 + quad) ^ l8) * 8)];
#pragma unroll
      for (int dt = 0; dt < 4; dt++) {
        const bf16x8 vf =
            *(const bf16x8*)&Vt[bi][(dt * 16 + l16) * 64 + (((c * 4 + quad) ^ l8) * 8)];
        o_acc[dt] = __builtin_amdgcn_mfma_f32_16x16x32_bf16(vf, pb, o_acc[dt], 0, 0, 0);
      }
    }
  }

  // epilogue: merge l chains, cross-quad reduce, normalize, packed 8B stores
  float l_i = (lacc[0] + lacc[1]) + (lacc[2] + lacc[3]);
  l_i += __shfl_xor(l_i, 16, 64);
  l_i += __shfl_xor(l_i, 32, 64);
  const float inv = 1.0f / l_i;
  unsigned short* orow = O + ((size_t)(b * SEQ + qrow)) * H + h * 64;
#pragma unroll
  for (int dt = 0; dt < 4; dt++) {
    uint2 d;
    d.x = pkbf(o_acc[dt][0] * inv, o_acc[dt][1] * inv);
    d.y = pkbf(o_acc[dt][2] * inv, o_acc[dt][3] * inv);
    *(uint2*)&orow[dt * 16 + quad * 4] = d;
  }
}

// ---------------------------------------------------------------------------
extern "C" void kernel_launch(void* const* d_in, const int* in_sizes, int n_in,
                              void* d_out, int out_size, void* d_ws, size_t ws_size,
                              hipStream_t stream) {
  const float* x = (const float*)d_in[0];
  const float* Wq = (const float*)d_in[1];
  const float* Wk = (const float*)d_in[2];
  const float* Wv = (const float*)d_in[3];
  const float* Wo = (const float*)d_in[4];
  const float* bo = (const float*)d_in[5];
  const float* gamma = (const float*)d_in[6];
  const float* beta = (const float*)d_in[7];
  float* out = (float*)d_out;

  unsigned short* ws = (unsigned short*)d_ws;
  unsigned short* xn = ws;                              // 4096*1024
  unsigned short* wcat = xn + (size_t)M_TOT * H;        // 4*1024*1024 (Wq,Wk,Wv,Wo)
  unsigned short* wob = wcat + (size_t)3 * H * H;
  unsigned short* qkb = wcat + (size_t)4 * H * H;       // 4096*2048 (Q | K)
  unsigned short* vtb = qkb + (size_t)M_TOT * 2048;     // 2*1024*2048 (V^T)
  unsigned short* atb = vtb + (size_t)BATCH * H * SEQ;  // 4096*1024

  ln_cast_kernel<<<M_TOT + 4096, 256, 0, stream>>>(x, gamma, beta, xn, Wq, Wk, Wv, Wo,
                                                   wcat);
  gemm128<0><<<dim3(M_TOT / 128, NQKV / 128), 256, 0, stream>>>(
      xn, wcat, qkb, vtb, nullptr, nullptr, nullptr);
  attn_kernel<<<dim3(SEQ / 64, NHEAD, BATCH), 256, 0, stream>>>(qkb, vtb, atb);
  gemm128<1><<<dim3(M_TOT / 128, H / 128), 256, 0, stream>>>(
      atb, wob, nullptr, nullptr, bo, x, out);
}

// Round 7
// 199.283 us; speedup vs baseline: 1.0853x; 1.0853x over previous
//
#include <hip/hip_runtime.h>
#include <hip/hip_bf16.h>

// Problem constants
#define H 1024
#define NHEAD 16
#define HDIM 64
#define SEQ 2048
#define BATCH 2
#define M_TOT (BATCH * SEQ) // 4096 tokens
#define NQKV 3072           // fused QKV output cols

typedef __attribute__((ext_vector_type(8))) short bf16x8; // 8 bf16 = 4 VGPRs (MFMA A/B frag)
typedef __attribute__((ext_vector_type(4))) float f32x4;  // MFMA C/D frag

// (1/sqrt(HDIM)) * log2(e), folded into Q at the QKV-GEMM epilogue
#define C2_SCALE 0.18033688f

__device__ __forceinline__ unsigned short f2bf(float f) {
  union { float f; unsigned int u; } a;
  a.f = f;
  unsigned int u = a.u;
  return (unsigned short)((u + 0x7fffu + ((u >> 16) & 1u)) >> 16); // RNE
}

// packed f32x2 -> bf16x2 (v_cvt_pk_bf16_f32), low short = first arg
__device__ __forceinline__ unsigned int pkbf(float a, float b) {
  union { __hip_bfloat162 h; unsigned int u; } cv;
  cv.h = __float22bfloat162_rn(float2{a, b});
  return cv.u;
}

__device__ __forceinline__ float fast_exp2(float x) {
#if defined(__has_builtin) && __has_builtin(__builtin_amdgcn_exp2f)
  return __builtin_amdgcn_exp2f(x);
#else
  return exp2f(x);
#endif
}

// async global->LDS, 16B per lane. LDS dest is wave-uniform base + lane*16.
typedef const __attribute__((address_space(1))) void* gas1_t;
typedef __attribute__((address_space(3))) void* las3_t;
__device__ __forceinline__ void gload16(const void* g, void* l) {
  __builtin_amdgcn_global_load_lds((gas1_t)(unsigned long long)g,
                                   (las3_t)(unsigned int)(unsigned long long)l,
                                   16, 0, 0);
}

// ---------------------------------------------------------------------------
// Kernel 1 (fused): LayerNorm rows (blocks 0..4095) + weight bf16 cast
// (blocks 4096..8191).
// ---------------------------------------------------------------------------
__global__ __launch_bounds__(256) void ln_cast_kernel(const float* __restrict__ x,
                                                      const float* __restrict__ gamma,
                                                      const float* __restrict__ beta,
                                                      unsigned short* __restrict__ xn,
                                                      const float* __restrict__ w0,
                                                      const float* __restrict__ w1,
                                                      const float* __restrict__ w2,
                                                      const float* __restrict__ w3,
                                                      unsigned short* __restrict__ wdst) {
  const int t = threadIdx.x;
  if (blockIdx.x >= M_TOT) {
    const int cb = blockIdx.x - M_TOT;   // 0..4095
    const int y = cb >> 10;              // matrix index 0..3
    const float* s = (y == 0) ? w0 : (y == 1) ? w1 : (y == 2) ? w2 : w3;
    const int i = (cb & 1023) * 256 + t; // float4 index within matrix
    const float4 v = ((const float4*)s)[i];
    ushort4 o;
    o.x = f2bf(v.x);
    o.y = f2bf(v.y);
    o.z = f2bf(v.z);
    o.w = f2bf(v.w);
    ((ushort4*)(wdst + (size_t)y * H * H))[i] = o;
    return;
  }
  const int row = blockIdx.x;
  const float* xr = x + (size_t)row * H;
  float4 v = ((const float4*)xr)[t];
  float s = v.x + v.y + v.z + v.w;
  float s2 = v.x * v.x + v.y * v.y + v.z * v.z + v.w * v.w;
#pragma unroll
  for (int o = 32; o; o >>= 1) {
    s += __shfl_xor(s, o, 64);
    s2 += __shfl_xor(s2, o, 64);
  }
  __shared__ float red[8];
  const int wave = t >> 6;
  if ((t & 63) == 0) {
    red[wave] = s;
    red[wave + 4] = s2;
  }
  __syncthreads();
  const float ts = red[0] + red[1] + red[2] + red[3];
  const float ts2 = red[4] + red[5] + red[6] + red[7];
  const float mu = ts * (1.0f / (float)H);
  const float var = ts2 * (1.0f / (float)H) - mu * mu;
  const float rstd = rsqrtf(var + 1e-5f);
  const float4 g = ((const float4*)gamma)[t];
  const float4 b = ((const float4*)beta)[t];
  ushort4 o;
  o.x = f2bf((v.x - mu) * rstd * g.x + b.x);
  o.y = f2bf((v.y - mu) * rstd * g.y + b.y);
  o.z = f2bf((v.z - mu) * rstd * g.z + b.z);
  o.w = f2bf((v.w - mu) * rstd * g.w + b.w);
  ((ushort4*)(xn + (size_t)row * H))[t] = o;
}

// ---------------------------------------------------------------------------
// 128x128x(BK=32) bf16 MFMA GEMM (round-5 structure: 16x16x32, 32 KB LDS,
// double-buffered, one barrier per K-iter, 4 blocks/CU).
// EPI=0: QKV epilogue. Q cols (<1024) scaled by C2_SCALE (softmax prescale).
//        cols<2048 -> qk natural; cols>=2048 -> V transposed vt[b][h*64+d][s].
// EPI=1: proj epilogue -> fp32 out = acc + bo[col] + x (residual).
// ---------------------------------------------------------------------------
template <int EPI>
__global__ __launch_bounds__(256, 4) void gemm128(const unsigned short* __restrict__ A,
                                                  const unsigned short* __restrict__ W,
                                                  unsigned short* __restrict__ qk,
                                                  unsigned short* __restrict__ vt,
                                                  const float* __restrict__ bo,
                                                  const float* __restrict__ x,
                                                  float* __restrict__ out) {
  const int m0 = blockIdx.x * 128;
  const int n0 = blockIdx.y * 128;
  const int tid = threadIdx.x;
  const int wave = tid >> 6;
  const int lane = tid & 63;
  const int l16 = lane & 15;
  const int quad = lane >> 4;
  const int wx = wave & 1, wy = wave >> 1;

  __shared__ __align__(16) unsigned short As[2][128 * 32];
  __shared__ __align__(16) unsigned short Bs[2][128 * 32];

  // staging: wave stages 32 rows (2 gload16 instrs per matrix)
  const int sub = lane >> 2;       // row within 16-row group
  const int kcol = (lane & 3) * 8; // 4 lanes cover 32 cols
  const unsigned short* ag = A + (size_t)(m0 + wave * 32 + sub) * H + kcol;
  const unsigned short* bg = W + (size_t)(n0 + wave * 32 + sub) * H + kcol;
  const int lofs = wave * 32 * 32;

  f32x4 acc[4][4] = {};

  // prologue: stage k0=0 into buffer 0
  gload16(ag, &As[0][lofs]);
  gload16(ag + 16 * H, &As[0][lofs + 16 * 32]);
  gload16(bg, &Bs[0][lofs]);
  gload16(bg + 16 * H, &Bs[0][lofs + 16 * 32]);

  for (int it = 0; it < H / 32; it++) {
    const int bi = it & 1;
    __syncthreads(); // drains buf[bi] loads (issued a full iter ago)
    if (it + 1 < H / 32) {
      const int k1 = (it + 1) * 32;
      gload16(ag + k1, &As[bi ^ 1][lofs]);
      gload16(ag + k1 + 16 * H, &As[bi ^ 1][lofs + 16 * 32]);
      gload16(bg + k1, &Bs[bi ^ 1][lofs]);
      gload16(bg + k1 + 16 * H, &Bs[bi ^ 1][lofs + 16 * 32]);
    }
    bf16x8 af[4], bf[4];
#pragma unroll
    for (int t = 0; t < 4; t++) {
      af[t] = *(const bf16x8*)&As[bi][(wy * 64 + t * 16 + l16) * 32 + quad * 8];
      bf[t] = *(const bf16x8*)&Bs[bi][(wx * 64 + t * 16 + l16) * 32 + quad * 8];
    }
#pragma unroll
    for (int i = 0; i < 4; i++)
#pragma unroll
      for (int j = 0; j < 4; j++)
        acc[i][j] = __builtin_amdgcn_mfma_f32_16x16x32_bf16(af[i], bf[j], acc[i][j], 0, 0, 0);
  }

  if (EPI == 0) {
#pragma unroll
    for (int j = 0; j < 4; j++) {
      const int cb = n0 + wx * 64 + j * 16; // wave-uniform tile col base
      if (cb < 2048) {
        const float qs = (cb < 1024) ? C2_SCALE : 1.0f;
#pragma unroll
        for (int i = 0; i < 4; i++) {
          const int row = m0 + wy * 64 + i * 16 + quad * 4;
#pragma unroll
          for (int r = 0; r < 4; r++)
            qk[(size_t)(row + r) * 2048 + cb + l16] = f2bf(acc[i][j][r] * qs);
        }
      } else {
        const int n = cb + l16 - 2048; // h*64+d
#pragma unroll
        for (int i = 0; i < 4; i++) {
          const int row0 = m0 + wy * 64 + i * 16 + quad * 4;
          const int b = row0 >> 11;
          const int s = row0 & 2047;
          ushort4 p;
          p.x = f2bf(acc[i][j][0]);
          p.y = f2bf(acc[i][j][1]);
          p.z = f2bf(acc[i][j][2]);
          p.w = f2bf(acc[i][j][3]);
          *(ushort4*)&vt[((size_t)b * 1024 + n) * SEQ + s] = p;
        }
      }
    }
  } else {
#pragma unroll
    for (int j = 0; j < 4; j++) {
      const int col = n0 + wx * 64 + j * 16 + l16;
      const float bv = bo[col];
#pragma unroll
      for (int i = 0; i < 4; i++) {
        const int row = m0 + wy * 64 + i * 16 + quad * 4;
#pragma unroll
        for (int r = 0; r < 4; r++) {
          const size_t idx = (size_t)(row + r) * H + col;
          out[idx] = acc[i][j][r] + bv + x[idx];
        }
      }
    }
  }
}

// ---------------------------------------------------------------------------
// Flash attention v4: LDS-bandwidth attack. Each wave handles TWO 16-q-row
// strips (32 q-rows); K-frag and V-frag LDS reads are register-reused across
// both strips -> LDS bytes per q-row drop from 1.5 KB to 0.81 KB.
// Block = 4 waves = 128 q-rows; grid (16, 16, 2) = 512 blocks (2/CU).
// S^T = K·Q^T / O^T = V^T·P^T, fixed-max softmax (p = exp2(s), M0=0).
// LDS 48 KB: Kt 16 + Vt 16 + Pt 16 (8 wave-private strips).
// ---------------------------------------------------------------------------
__global__ __launch_bounds__(256, 2) void attn_kernel(const unsigned short* __restrict__ qk,
                                                      const unsigned short* __restrict__ vt,
                                                      unsigned short* __restrict__ O) {
  const int qt = blockIdx.x;
  const int h = blockIdx.y;
  const int b = blockIdx.z;
  const int tid = threadIdx.x;
  const int wave = tid >> 6;
  const int lane = tid & 63;
  const int l16 = lane & 15;
  const int quad = lane >> 4;
  const int l8 = l16 & 7;

  __shared__ __align__(16) unsigned short Kt[2][64 * 64];
  __shared__ __align__(16) unsigned short Vt[2][64 * 64]; // [d][s]
  __shared__ __align__(16) unsigned short Pt[8][16 * 64]; // per-(wave,u) strips

  const unsigned short* Qbase = qk + (size_t)b * SEQ * 2048 + h * 64;
  const unsigned short* Kbase = qk + (size_t)b * SEQ * 2048 + 1024 + h * 64;
  const unsigned short* Vbase = vt + ((size_t)b * 1024 + h * 64) * SEQ;

  // staging geometry: one gload16 covers 8 rows x 64 shorts (1 KB), XOR swizzle
  const int rIn = lane >> 3;
  const int gsw = (lane & 7) ^ rIn;
  const int ch0 = 2 * wave;

  // Q fragments for both strips (B-operand): B[n=l16 -> qrow][k=quad*8+j -> d]
  const int qrow0 = qt * 128 + wave * 32 + l16; // strip u: +u*16
  bf16x8 aq[2][2];                              // [u][c]
#pragma unroll
  for (int u = 0; u < 2; u++)
#pragma unroll
    for (int c = 0; c < 2; c++)
      aq[u][c] = *(const bf16x8*)(Qbase + (size_t)(qrow0 + u * 16) * 2048 + c * 32 + quad * 8);

  float lacc[2][2] = {};  // [u][chain] partial denominators
  f32x4 o_acc[2][4] = {}; // [u][dt] O^T: col=l16=qrow, row=quad*4+r -> d

  // prologue: stage tile 0 into buffer 0
#pragma unroll
  for (int c = 0; c < 2; c++) {
    const int ch = ch0 + c;
    const int row = ch * 8 + rIn;
    gload16(Kbase + (size_t)row * 2048 + gsw * 8, &Kt[0][ch * 512]);
    gload16(Vbase + (size_t)row * SEQ + gsw * 8, &Vt[0][ch * 512]);
  }

  unsigned short* myP0 = &Pt[wave * 2 + 0][0];
  unsigned short* myP1 = &Pt[wave * 2 + 1][0];

#pragma unroll 2
  for (int it = 0; it < SEQ / 64; it++) {
    const int bi = it & 1;
    __syncthreads(); // waits cur-buffer loads (vmcnt) + prev iter readers done
    if (it + 1 < SEQ / 64) {
#pragma unroll
      for (int c = 0; c < 2; c++) {
        const int ch = ch0 + c;
        const int row = ch * 8 + rIn;
        gload16(Kbase + (size_t)((it + 1) * 64 + row) * 2048 + gsw * 8,
                &Kt[bi ^ 1][ch * 512]);
        gload16(Vbase + (size_t)row * SEQ + (it + 1) * 64 + gsw * 8,
                &Vt[bi ^ 1][ch * 512]);
      }
    }

    // S^T = K (A) @ Q^T (B): K-frag read ONCE, reused for both q-strips
    f32x4 s[2][4] = {};
#pragma unroll
    for (int c = 0; c < 2; c++) {
#pragma unroll
      for (int t = 0; t < 4; t++) {
        const bf16x8 kf =
            *(const bf16x8*)&Kt[bi][(t * 16 + l16) * 64 + (((c * 4 + quad) ^ l8) * 8)];
        s[0][t] = __builtin_amdgcn_mfma_f32_16x16x32_bf16(kf, aq[0][c], s[0][t], 0, 0, 0);
        s[1][t] = __builtin_amdgcn_mfma_f32_16x16x32_bf16(kf, aq[1][c], s[1][t], 0, 0, 0);
      }
    }

    // fixed-max softmax: p = exp2(s); independent l-chains
    float pv[2][4][4];
#pragma unroll
    for (int u = 0; u < 2; u++)
#pragma unroll
      for (int t = 0; t < 4; t++) {
#pragma unroll
        for (int r = 0; r < 4; r++) pv[u][t][r] = fast_exp2(s[u][t][r]);
        lacc[u][t & 1] += (pv[u][t][0] + pv[u][t][1]) + (pv[u][t][2] + pv[u][t][3]);
      }

    // P^T strips -> wave-private LDS (natural P layout [qrow][s]), b64 writes
#pragma unroll
    for (int t = 0; t < 4; t++) {
      const int wofs = l16 * 64 + (((t * 2 + (quad >> 1)) ^ l8) * 8) + (quad & 1) * 4;
      uint2 d0, d1;
      d0.x = pkbf(pv[0][t][0], pv[0][t][1]);
      d0.y = pkbf(pv[0][t][2], pv[0][t][3]);
      d1.x = pkbf(pv[1][t][0], pv[1][t][1]);
      d1.y = pkbf(pv[1][t][2], pv[1][t][3]);
      *(uint2*)&myP0[wofs] = d0;
      *(uint2*)&myP1[wofs] = d1;
    }

    // O^T += V^T (A) @ P^T (B): V-frag read ONCE, reused for both q-strips
#pragma unroll
    for (int c = 0; c < 2; c++) {
      const int rofs = l16 * 64 + (((c * 4 + quad) ^ l8) * 8);
      const bf16x8 pb0 = *(const bf16x8*)&myP0[rofs];
      const bf16x8 pb1 = *(const bf16x8*)&myP1[rofs];
#pragma unroll
      for (int dt = 0; dt < 4; dt++) {
        const bf16x8 vf =
            *(const bf16x8*)&Vt[bi][(dt * 16 + l16) * 64 + (((c * 4 + quad) ^ l8) * 8)];
        o_acc[0][dt] = __builtin_amdgcn_mfma_f32_16x16x32_bf16(vf, pb0, o_acc[0][dt], 0, 0, 0);
        o_acc[1][dt] = __builtin_amdgcn_mfma_f32_16x16x32_bf16(vf, pb1, o_acc[1][dt], 0, 0, 0);
      }
    }
  }

  // epilogue: per-strip l reduce, normalize, packed 8B stores
#pragma unroll
  for (int u = 0; u < 2; u++) {
    float l_i = lacc[u][0] + lacc[u][1];
    l_i += __shfl_xor(l_i, 16, 64);
    l_i += __shfl_xor(l_i, 32, 64);
    const float inv = 1.0f / l_i;
    unsigned short* orow = O + ((size_t)(b * SEQ + qrow0 + u * 16)) * H + h * 64;
#pragma unroll
    for (int dt = 0; dt < 4; dt++) {
      uint2 d;
      d.x = pkbf(o_acc[u][dt][0] * inv, o_acc[u][dt][1] * inv);
      d.y = pkbf(o_acc[u][dt][2] * inv, o_acc[u][dt][3] * inv);
      *(uint2*)&orow[dt * 16 + quad * 4] = d;
    }
  }
}

// ---------------------------------------------------------------------------
extern "C" void kernel_launch(void* const* d_in, const int* in_sizes, int n_in,
                              void* d_out, int out_size, void* d_ws, size_t ws_size,
                              hipStream_t stream) {
  const float* x = (const float*)d_in[0];
  const float* Wq = (const float*)d_in[1];
  const float* Wk = (const float*)d_in[2];
  const float* Wv = (const float*)d_in[3];
  const float* Wo = (const float*)d_in[4];
  const float* bo = (const float*)d_in[5];
  const float* gamma = (const float*)d_in[6];
  const float* beta = (const float*)d_in[7];
  float* out = (float*)d_out;

  unsigned short* ws = (unsigned short*)d_ws;
  unsigned short* xn = ws;                              // 4096*1024
  unsigned short* wcat = xn + (size_t)M_TOT * H;        // 4*1024*1024 (Wq,Wk,Wv,Wo)
  unsigned short* wob = wcat + (size_t)3 * H * H;
  unsigned short* qkb = wcat + (size_t)4 * H * H;       // 4096*2048 (Q | K)
  unsigned short* vtb = qkb + (size_t)M_TOT * 2048;     // 2*1024*2048 (V^T)
  unsigned short* atb = vtb + (size_t)BATCH * H * SEQ;  // 4096*1024

  ln_cast_kernel<<<M_TOT + 4096, 256, 0, stream>>>(x, gamma, beta, xn, Wq, Wk, Wv, Wo,
                                                   wcat);
  gemm128<0><<<dim3(M_TOT / 128, NQKV / 128), 256, 0, stream>>>(
      xn, wcat, qkb, vtb, nullptr, nullptr, nullptr);
  attn_kernel<<<dim3(SEQ / 128, NHEAD, BATCH), 256, 0, stream>>>(qkb, vtb, atb);
  gemm128<1><<<dim3(M_TOT / 128, H / 128), 256, 0, stream>>>(
      atb, wob, nullptr, nullptr, bo, x, out);
}

// Round 8
// 195.720 us; speedup vs baseline: 1.1051x; 1.0182x over previous
//
#include <hip/hip_runtime.h>
#include <hip/hip_bf16.h>

// Problem constants
#define H 1024
#define NHEAD 16
#define HDIM 64
#define SEQ 2048
#define BATCH 2
#define M_TOT (BATCH * SEQ) // 4096 tokens
#define NQKV 3072           // fused QKV output cols

typedef __attribute__((ext_vector_type(8))) short bf16x8; // 8 bf16 = 4 VGPRs (MFMA A/B frag)
typedef __attribute__((ext_vector_type(4))) float f32x4;  // MFMA C/D frag

// (1/sqrt(HDIM)) * log2(e), folded into Q at the QKV-GEMM epilogue
#define C2_SCALE 0.18033688f

__device__ __forceinline__ unsigned short f2bf(float f) {
  union { float f; unsigned int u; } a;
  a.f = f;
  unsigned int u = a.u;
  return (unsigned short)((u + 0x7fffu + ((u >> 16) & 1u)) >> 16); // RNE
}

// packed f32x2 -> bf16x2 (v_cvt_pk_bf16_f32), low short = first arg
__device__ __forceinline__ unsigned int pkbf(float a, float b) {
  union { __hip_bfloat162 h; unsigned int u; } cv;
  cv.h = __float22bfloat162_rn(float2{a, b});
  return cv.u;
}

__device__ __forceinline__ float fast_exp2(float x) {
#if defined(__has_builtin) && __has_builtin(__builtin_amdgcn_exp2f)
  return __builtin_amdgcn_exp2f(x);
#else
  return exp2f(x);
#endif
}

// async global->LDS, 16B per lane. LDS dest is wave-uniform base + lane*16.
typedef const __attribute__((address_space(1))) void* gas1_t;
typedef __attribute__((address_space(3))) void* las3_t;
__device__ __forceinline__ void gload16(const void* g, void* l) {
  __builtin_amdgcn_global_load_lds((gas1_t)(unsigned long long)g,
                                   (las3_t)(unsigned int)(unsigned long long)l,
                                   16, 0, 0);
}

// ---------------------------------------------------------------------------
// Kernel 1 (fused): LayerNorm rows (blocks 0..4095) + weight bf16 cast
// (blocks 4096..8191).
// ---------------------------------------------------------------------------
__global__ __launch_bounds__(256) void ln_cast_kernel(const float* __restrict__ x,
                                                      const float* __restrict__ gamma,
                                                      const float* __restrict__ beta,
                                                      unsigned short* __restrict__ xn,
                                                      const float* __restrict__ w0,
                                                      const float* __restrict__ w1,
                                                      const float* __restrict__ w2,
                                                      const float* __restrict__ w3,
                                                      unsigned short* __restrict__ wdst) {
  const int t = threadIdx.x;
  if (blockIdx.x >= M_TOT) {
    const int cb = blockIdx.x - M_TOT;   // 0..4095
    const int y = cb >> 10;              // matrix index 0..3
    const float* s = (y == 0) ? w0 : (y == 1) ? w1 : (y == 2) ? w2 : w3;
    const int i = (cb & 1023) * 256 + t; // float4 index within matrix
    const float4 v = ((const float4*)s)[i];
    ushort4 o;
    o.x = f2bf(v.x);
    o.y = f2bf(v.y);
    o.z = f2bf(v.z);
    o.w = f2bf(v.w);
    ((ushort4*)(wdst + (size_t)y * H * H))[i] = o;
    return;
  }
  const int row = blockIdx.x;
  const float* xr = x + (size_t)row * H;
  float4 v = ((const float4*)xr)[t];
  float s = v.x + v.y + v.z + v.w;
  float s2 = v.x * v.x + v.y * v.y + v.z * v.z + v.w * v.w;
#pragma unroll
  for (int o = 32; o; o >>= 1) {
    s += __shfl_xor(s, o, 64);
    s2 += __shfl_xor(s2, o, 64);
  }
  __shared__ float red[8];
  const int wave = t >> 6;
  if ((t & 63) == 0) {
    red[wave] = s;
    red[wave + 4] = s2;
  }
  __syncthreads();
  const float ts = red[0] + red[1] + red[2] + red[3];
  const float ts2 = red[4] + red[5] + red[6] + red[7];
  const float mu = ts * (1.0f / (float)H);
  const float var = ts2 * (1.0f / (float)H) - mu * mu;
  const float rstd = rsqrtf(var + 1e-5f);
  const float4 g = ((const float4*)gamma)[t];
  const float4 b = ((const float4*)beta)[t];
  ushort4 o;
  o.x = f2bf((v.x - mu) * rstd * g.x + b.x);
  o.y = f2bf((v.y - mu) * rstd * g.y + b.y);
  o.z = f2bf((v.z - mu) * rstd * g.z + b.z);
  o.w = f2bf((v.w - mu) * rstd * g.w + b.w);
  ((ushort4*)(xn + (size_t)row * H))[t] = o;
}

// ---------------------------------------------------------------------------
// 128x128x(BK=32) bf16 MFMA GEMM (16x16x32, 32 KB LDS, double-buffered,
// one barrier per K-iter, 4 blocks/CU) with XCD-AWARE 1-D GRID:
//   xcd = id & 7; each XCD owns NPX consecutive N-blocks (W-slice stays in
//   its 4 MB L2); M-blocks iterate within the XCD.
// EPI=0 (NPX=3): QKV epilogue. Q cols (<1024) scaled by C2_SCALE.
//        cols<2048 -> qk natural; cols>=2048 -> V transposed vt[b][h*64+d][s].
// EPI=1 (NPX=1): proj epilogue -> fp32 out = acc + bo[col] + x (residual).
// ---------------------------------------------------------------------------
template <int EPI, int NPX>
__global__ __launch_bounds__(256, 4) void gemm128(const unsigned short* __restrict__ A,
                                                  const unsigned short* __restrict__ W,
                                                  unsigned short* __restrict__ qk,
                                                  unsigned short* __restrict__ vt,
                                                  const float* __restrict__ bo,
                                                  const float* __restrict__ x,
                                                  float* __restrict__ out) {
  const int id = blockIdx.x;
  const int xcd = id & 7;
  const int r = id >> 3;
  const int nb = xcd * NPX + (r % NPX);
  const int mb = r / NPX;
  const int m0 = mb * 128;
  const int n0 = nb * 128;
  const int tid = threadIdx.x;
  const int wave = tid >> 6;
  const int lane = tid & 63;
  const int l16 = lane & 15;
  const int quad = lane >> 4;
  const int wx = wave & 1, wy = wave >> 1;

  __shared__ __align__(16) unsigned short As[2][128 * 32];
  __shared__ __align__(16) unsigned short Bs[2][128 * 32];

  // staging: wave stages 32 rows (2 gload16 instrs per matrix)
  const int sub = lane >> 2;       // row within 16-row group
  const int kcol = (lane & 3) * 8; // 4 lanes cover 32 cols
  const unsigned short* ag = A + (size_t)(m0 + wave * 32 + sub) * H + kcol;
  const unsigned short* bg = W + (size_t)(n0 + wave * 32 + sub) * H + kcol;
  const int lofs = wave * 32 * 32;

  f32x4 acc[4][4] = {};

  // prologue: stage k0=0 into buffer 0
  gload16(ag, &As[0][lofs]);
  gload16(ag + 16 * H, &As[0][lofs + 16 * 32]);
  gload16(bg, &Bs[0][lofs]);
  gload16(bg + 16 * H, &Bs[0][lofs + 16 * 32]);

  for (int it = 0; it < H / 32; it++) {
    const int bi = it & 1;
    __syncthreads(); // drains buf[bi] loads (issued a full iter ago)
    if (it + 1 < H / 32) {
      const int k1 = (it + 1) * 32;
      gload16(ag + k1, &As[bi ^ 1][lofs]);
      gload16(ag + k1 + 16 * H, &As[bi ^ 1][lofs + 16 * 32]);
      gload16(bg + k1, &Bs[bi ^ 1][lofs]);
      gload16(bg + k1 + 16 * H, &Bs[bi ^ 1][lofs + 16 * 32]);
    }
    bf16x8 af[4], bf[4];
#pragma unroll
    for (int t = 0; t < 4; t++) {
      af[t] = *(const bf16x8*)&As[bi][(wy * 64 + t * 16 + l16) * 32 + quad * 8];
      bf[t] = *(const bf16x8*)&Bs[bi][(wx * 64 + t * 16 + l16) * 32 + quad * 8];
    }
#pragma unroll
    for (int i = 0; i < 4; i++)
#pragma unroll
      for (int j = 0; j < 4; j++)
        acc[i][j] = __builtin_amdgcn_mfma_f32_16x16x32_bf16(af[i], bf[j], acc[i][j], 0, 0, 0);
  }

  if (EPI == 0) {
#pragma unroll
    for (int j = 0; j < 4; j++) {
      const int cb = n0 + wx * 64 + j * 16; // wave-uniform tile col base
      if (cb < 2048) {
        const float qs = (cb < 1024) ? C2_SCALE : 1.0f;
#pragma unroll
        for (int i = 0; i < 4; i++) {
          const int row = m0 + wy * 64 + i * 16 + quad * 4;
#pragma unroll
          for (int r2 = 0; r2 < 4; r2++)
            qk[(size_t)(row + r2) * 2048 + cb + l16] = f2bf(acc[i][j][r2] * qs);
        }
      } else {
        const int n = cb + l16 - 2048; // h*64+d
#pragma unroll
        for (int i = 0; i < 4; i++) {
          const int row0 = m0 + wy * 64 + i * 16 + quad * 4;
          const int b = row0 >> 11;
          const int s = row0 & 2047;
          ushort4 p;
          p.x = f2bf(acc[i][j][0]);
          p.y = f2bf(acc[i][j][1]);
          p.z = f2bf(acc[i][j][2]);
          p.w = f2bf(acc[i][j][3]);
          *(ushort4*)&vt[((size_t)b * 1024 + n) * SEQ + s] = p;
        }
      }
    }
  } else {
#pragma unroll
    for (int j = 0; j < 4; j++) {
      const int col = n0 + wx * 64 + j * 16 + l16;
      const float bv = bo[col];
#pragma unroll
      for (int i = 0; i < 4; i++) {
        const int row = m0 + wy * 64 + i * 16 + quad * 4;
#pragma unroll
        for (int r2 = 0; r2 < 4; r2++) {
          const size_t idx = (size_t)(row + r2) * H + col;
          out[idx] = acc[i][j][r2] + bv + x[idx];
        }
      }
    }
  }
}

// ---------------------------------------------------------------------------
// Flash attention v4.1: identical compute to v4 (2 q-strips/wave, fixed-max
// softmax, S^T/O^T formulation) + XCD-aware 1-D grid: each XCD owns 4 (b,h)
// combos x all 16 q-tiles -> its K/V slice (2 MB) stays in its L2.
// ---------------------------------------------------------------------------
__global__ __launch_bounds__(256, 2) void attn_kernel(const unsigned short* __restrict__ qk,
                                                      const unsigned short* __restrict__ vt,
                                                      unsigned short* __restrict__ O) {
  const int id = blockIdx.x; // 512 blocks
  const int xcd = id & 7;
  const int slot = id >> 3;       // 0..63
  const int qt = slot & 15;       // q-tile within (b,h)
  const int g = slot >> 4;        // 0..3
  const int combo = xcd * 4 + g;  // 0..31
  const int h = combo & 15;
  const int b = combo >> 4;
  const int tid = threadIdx.x;
  const int wave = tid >> 6;
  const int lane = tid & 63;
  const int l16 = lane & 15;
  const int quad = lane >> 4;
  const int l8 = l16 & 7;

  __shared__ __align__(16) unsigned short Kt[2][64 * 64];
  __shared__ __align__(16) unsigned short Vt[2][64 * 64]; // [d][s]
  __shared__ __align__(16) unsigned short Pt[8][16 * 64]; // per-(wave,u) strips

  const unsigned short* Qbase = qk + (size_t)b * SEQ * 2048 + h * 64;
  const unsigned short* Kbase = qk + (size_t)b * SEQ * 2048 + 1024 + h * 64;
  const unsigned short* Vbase = vt + ((size_t)b * 1024 + h * 64) * SEQ;

  // staging geometry: one gload16 covers 8 rows x 64 shorts (1 KB), XOR swizzle
  const int rIn = lane >> 3;
  const int gsw = (lane & 7) ^ rIn;
  const int ch0 = 2 * wave;

  // Q fragments for both strips (B-operand): B[n=l16 -> qrow][k=quad*8+j -> d]
  const int qrow0 = qt * 128 + wave * 32 + l16; // strip u: +u*16
  bf16x8 aq[2][2];                              // [u][c]
#pragma unroll
  for (int u = 0; u < 2; u++)
#pragma unroll
    for (int c = 0; c < 2; c++)
      aq[u][c] = *(const bf16x8*)(Qbase + (size_t)(qrow0 + u * 16) * 2048 + c * 32 + quad * 8);

  float lacc[2][2] = {};  // [u][chain] partial denominators
  f32x4 o_acc[2][4] = {}; // [u][dt] O^T: col=l16=qrow, row=quad*4+r -> d

  // prologue: stage tile 0 into buffer 0
#pragma unroll
  for (int c = 0; c < 2; c++) {
    const int ch = ch0 + c;
    const int row = ch * 8 + rIn;
    gload16(Kbase + (size_t)row * 2048 + gsw * 8, &Kt[0][ch * 512]);
    gload16(Vbase + (size_t)row * SEQ + gsw * 8, &Vt[0][ch * 512]);
  }

  unsigned short* myP0 = &Pt[wave * 2 + 0][0];
  unsigned short* myP1 = &Pt[wave * 2 + 1][0];

#pragma unroll 2
  for (int it = 0; it < SEQ / 64; it++) {
    const int bi = it & 1;
    __syncthreads(); // waits cur-buffer loads (vmcnt) + prev iter readers done
    if (it + 1 < SEQ / 64) {
#pragma unroll
      for (int c = 0; c < 2; c++) {
        const int ch = ch0 + c;
        const int row = ch * 8 + rIn;
        gload16(Kbase + (size_t)((it + 1) * 64 + row) * 2048 + gsw * 8,
                &Kt[bi ^ 1][ch * 512]);
        gload16(Vbase + (size_t)row * SEQ + (it + 1) * 64 + gsw * 8,
                &Vt[bi ^ 1][ch * 512]);
      }
    }

    // S^T = K (A) @ Q^T (B): K-frag read ONCE, reused for both q-strips
    f32x4 s[2][4] = {};
#pragma unroll
    for (int c = 0; c < 2; c++) {
#pragma unroll
      for (int t = 0; t < 4; t++) {
        const bf16x8 kf =
            *(const bf16x8*)&Kt[bi][(t * 16 + l16) * 64 + (((c * 4 + quad) ^ l8) * 8)];
        s[0][t] = __builtin_amdgcn_mfma_f32_16x16x32_bf16(kf, aq[0][c], s[0][t], 0, 0, 0);
        s[1][t] = __builtin_amdgcn_mfma_f32_16x16x32_bf16(kf, aq[1][c], s[1][t], 0, 0, 0);
      }
    }

    // fixed-max softmax: p = exp2(s); independent l-chains
    float pv[2][4][4];
#pragma unroll
    for (int u = 0; u < 2; u++)
#pragma unroll
      for (int t = 0; t < 4; t++) {
#pragma unroll
        for (int r = 0; r < 4; r++) pv[u][t][r] = fast_exp2(s[u][t][r]);
        lacc[u][t & 1] += (pv[u][t][0] + pv[u][t][1]) + (pv[u][t][2] + pv[u][t][3]);
      }

    // P^T strips -> wave-private LDS (natural P layout [qrow][s]), b64 writes
#pragma unroll
    for (int t = 0; t < 4; t++) {
      const int wofs = l16 * 64 + (((t * 2 + (quad >> 1)) ^ l8) * 8) + (quad & 1) * 4;
      uint2 d0, d1;
      d0.x = pkbf(pv[0][t][0], pv[0][t][1]);
      d0.y = pkbf(pv[0][t][2], pv[0][t][3]);
      d1.x = pkbf(pv[1][t][0], pv[1][t][1]);
      d1.y = pkbf(pv[1][t][2], pv[1][t][3]);
      *(uint2*)&myP0[wofs] = d0;
      *(uint2*)&myP1[wofs] = d1;
    }

    // O^T += V^T (A) @ P^T (B): V-frag read ONCE, reused for both q-strips
#pragma unroll
    for (int c = 0; c < 2; c++) {
      const int rofs = l16 * 64 + (((c * 4 + quad) ^ l8) * 8);
      const bf16x8 pb0 = *(const bf16x8*)&myP0[rofs];
      const bf16x8 pb1 = *(const bf16x8*)&myP1[rofs];
#pragma unroll
      for (int dt = 0; dt < 4; dt++) {
        const bf16x8 vf =
            *(const bf16x8*)&Vt[bi][(dt * 16 + l16) * 64 + (((c * 4 + quad) ^ l8) * 8)];
        o_acc[0][dt] = __builtin_amdgcn_mfma_f32_16x16x32_bf16(vf, pb0, o_acc[0][dt], 0, 0, 0);
        o_acc[1][dt] = __builtin_amdgcn_mfma_f32_16x16x32_bf16(vf, pb1, o_acc[1][dt], 0, 0, 0);
      }
    }
  }

  // epilogue: per-strip l reduce, normalize, packed 8B stores
#pragma unroll
  for (int u = 0; u < 2; u++) {
    float l_i = lacc[u][0] + lacc[u][1];
    l_i += __shfl_xor(l_i, 16, 64);
    l_i += __shfl_xor(l_i, 32, 64);
    const float inv = 1.0f / l_i;
    unsigned short* orow = O + ((size_t)(b * SEQ + qrow0 + u * 16)) * H + h * 64;
#pragma unroll
    for (int dt = 0; dt < 4; dt++) {
      uint2 d;
      d.x = pkbf(o_acc[u][dt][0] * inv, o_acc[u][dt][1] * inv);
      d.y = pkbf(o_acc[u][dt][2] * inv, o_acc[u][dt][3] * inv);
      *(uint2*)&orow[dt * 16 + quad * 4] = d;
    }
  }
}

// ---------------------------------------------------------------------------
extern "C" void kernel_launch(void* const* d_in, const int* in_sizes, int n_in,
                              void* d_out, int out_size, void* d_ws, size_t ws_size,
                              hipStream_t stream) {
  const float* x = (const float*)d_in[0];
  const float* Wq = (const float*)d_in[1];
  const float* Wk = (const float*)d_in[2];
  const float* Wv = (const float*)d_in[3];
  const float* Wo = (const float*)d_in[4];
  const float* bo = (const float*)d_in[5];
  const float* gamma = (const float*)d_in[6];
  const float* beta = (const float*)d_in[7];
  float* out = (float*)d_out;

  unsigned short* ws = (unsigned short*)d_ws;
  unsigned short* xn = ws;                              // 4096*1024
  unsigned short* wcat = xn + (size_t)M_TOT * H;        // 4*1024*1024 (Wq,Wk,Wv,Wo)
  unsigned short* wob = wcat + (size_t)3 * H * H;
  unsigned short* qkb = wcat + (size_t)4 * H * H;       // 4096*2048 (Q | K)
  unsigned short* vtb = qkb + (size_t)M_TOT * 2048;     // 2*1024*2048 (V^T)
  unsigned short* atb = vtb + (size_t)BATCH * H * SEQ;  // 4096*1024

  ln_cast_kernel<<<M_TOT + 4096, 256, 0, stream>>>(x, gamma, beta, xn, Wq, Wk, Wv, Wo,
                                                   wcat);
  // QKV: 32 M-blocks x 24 N-blocks, XCD-supertiled (3 N-blocks per XCD)
  gemm128<0, 3><<<(M_TOT / 128) * (NQKV / 128), 256, 0, stream>>>(
      xn, wcat, qkb, vtb, nullptr, nullptr, nullptr);
  // attn: 512 blocks, XCD-supertiled (4 (b,h) combos per XCD)
  attn_kernel<<<(SEQ / 128) * NHEAD * BATCH, 256, 0, stream>>>(qkb, vtb, atb);
  // proj: 32 M-blocks x 8 N-blocks, XCD-supertiled (1 N-block per XCD)
  gemm128<1, 1><<<(M_TOT / 128) * (H / 128), 256, 0, stream>>>(
      atb, wob, nullptr, nullptr, bo, x, out);
}